// Round 7
// baseline (92.479 us; speedup 1.0000x reference)
//
#include <hip/hip_runtime.h>

#define B_ 16
#define C_ 256
#define P_ 2048
#define BK 32
#define NT 136      // tiles per batch (120 strict-upper + 16 diag)
#define NT_OFF 120

typedef __attribute__((ext_vector_type(8))) short short8;
typedef __attribute__((ext_vector_type(4))) float floatx4;

// round-to-nearest-even fp32 -> bf16
__device__ inline short f2bf(float v) {
  union { float f; unsigned u; } c; c.f = v;
  unsigned r = c.u + 0x7fffu + ((c.u >> 16) & 1u);
  return (short)(r >> 16);
}

#define GLOAD_LDS16(g, l)                                          \
  __builtin_amdgcn_global_load_lds(                                \
      (const __attribute__((address_space(1))) void*)(g),          \
      (__attribute__((address_space(3))) void*)(l), 16, 0, 0)

// ---------------- kernel 1: transpose + fp32->bf16 + exact norms ----------------
// One block owns a 32-wide p-stripe for one batch; loops all 8 c-chunks.
// No atomics, no memset needed.
__global__ __launch_bounds__(256, 4) void k_transpose(const float* __restrict__ x,
                                                      short* __restrict__ Xt,
                                                      float* __restrict__ nrm2) {
  __shared__ float t[32][33];
  __shared__ float red[8][32];
  const int p0 = blockIdx.x * 32, b = blockIdx.y;
  const float* xb = x + (size_t)b * C_ * P_;
  short* xtb = Xt + (size_t)b * P_ * C_;
  const int tx = threadIdx.x, ty = threadIdx.y;  // block dim3(32,8)
  const int tid = ty * 32 + tx;
  const int r = tid >> 3, ch = tid & 7;
  float s = 0.f;
#pragma unroll 1
  for (int ci = 0; ci < 8; ++ci) {
    const int c0 = ci * 32;
#pragma unroll
    for (int i = 0; i < 4; ++i) {
      float v = xb[(size_t)(c0 + ty + i * 8) * P_ + p0 + tx];
      t[ty + i * 8][tx] = v;
      s += v * v;  // thread's partial: col p0+tx, 4 c's per iter
    }
    __syncthreads();
    short4 w;
    w.x = f2bf(t[ch * 4 + 0][r]);
    w.y = f2bf(t[ch * 4 + 1][r]);
    w.z = f2bf(t[ch * 4 + 2][r]);
    w.w = f2bf(t[ch * 4 + 3][r]);
    *reinterpret_cast<short4*>(&xtb[(size_t)(p0 + r) * C_ + c0 + ch * 4]) = w;
    __syncthreads();  // protect t before next iteration overwrites it
  }
  red[ty][tx] = s;
  __syncthreads();
  if (tid < 32) {
    float ns = 0.f;
#pragma unroll
    for (int j = 0; j < 8; ++j) ns += red[j][tid];
    nrm2[b * P_ + p0 + tid] = ns;  // exact (all 256 c summed here)
  }
}

// ---------------- kernel 2: symmetric Gram GEMM, XCD-chunked ----------------
__global__ __launch_bounds__(256, 4) void k_gemm(const short* __restrict__ Xt,
                                                 const float* __restrict__ nrm2,
                                                 float* __restrict__ out) {
  // XCD-chunked mapping: xcd = bid%8 owns 2 full batches -> Xt working set L2-resident
  const int bid = blockIdx.x;
  const int xcd = bid & 7;
  const int s = bid >> 3;              // 0..271
  const int b = xcd * 2 + (s >= NT);   // 2 batches per XCD
  int t = s - (s >= NT ? NT : 0);      // 0..135

  int tm, tn;
  if (t < NT_OFF) {  // strict-upper tiles (2 writes) first
    int rem = t, len = 15;
    tm = 0;
    while (rem >= len) { rem -= len; --len; ++tm; }
    tn = tm + 1 + rem;
  } else {
    tm = tn = t - NT_OFF;
  }
  const int p0 = tm * 128, q0 = tn * 128;
  const short* Xb = Xt + (size_t)b * P_ * C_;

  __shared__ __align__(16) char smem[32768];  // As[2][8K] | Bs[2][8K]; epilogue reuse

  const int tid = threadIdx.x;
  const int lane = tid & 63;
  const int wid = tid >> 6;
  const int wrow = wid >> 1;  // p band (64)
  const int wcol = wid & 1;   // q band (64)

  floatx4 acc[4][4];
#pragma unroll
  for (int i = 0; i < 4; ++i)
#pragma unroll
    for (int j = 0; j < 4; ++j) acc[i][j] = (floatx4){0.f, 0.f, 0.f, 0.f};

  const int K2 = C_ * 2;  // row stride bytes

  auto STAGE = [&](int buf, int kt) {
    const int kb = kt * (BK * 2);
#pragma unroll
    for (int j = 0; j < 2; ++j) {
      const int chunk = j * 4 + wid;           // 0..7, wave-uniform
      const int f = chunk * 1024 + lane * 16;
      const int row = f >> 6;
      const int inrow = f & 63;
      GLOAD_LDS16((const char*)Xb + (size_t)(p0 + row) * K2 + kb + inrow,
                  smem + buf * 8192 + chunk * 1024);
      GLOAD_LDS16((const char*)Xb + (size_t)(q0 + row) * K2 + kb + inrow,
                  smem + 16384 + buf * 8192 + chunk * 1024);
    }
  };

  STAGE(0, 0);
  asm volatile("s_waitcnt vmcnt(0)\n\ts_barrier" ::: "memory");

  // Single barrier per K-step. End-of-iter asm enforces BOTH completions before
  // anyone proceeds: vmcnt(0) -> next tile fully staged; lgkmcnt(0) -> this
  // wave's ds_reads of cur are complete (issue-before-barrier is NOT completion
  // -- the r3-r5 race). MFMAs may sink below the barrier; they're register-only.
  for (int kt = 0; kt < C_ / BK; ++kt) {
    const int cur = kt & 1;
    if (kt < C_ / BK - 1) STAGE(cur ^ 1, kt + 1);

    const short* As = (const short*)(smem + cur * 8192);
    const short* Bs = (const short*)(smem + 16384 + cur * 8192);
    short8 af[4], bf[4];
#pragma unroll
    for (int mi = 0; mi < 4; ++mi) {
      const int r = wrow * 64 + mi * 16 + (lane & 15);
      af[mi] = *reinterpret_cast<const short8*>(&As[r * BK + (lane >> 4) * 8]);
    }
#pragma unroll
    for (int ni = 0; ni < 4; ++ni) {
      const int r = wcol * 64 + ni * 16 + (lane & 15);
      bf[ni] = *reinterpret_cast<const short8*>(&Bs[r * BK + (lane >> 4) * 8]);
    }
    // D[row=p][col=q]; C/D layout: col=lane&15, row=(lane>>4)*4+reg (verified r1)
#pragma unroll
    for (int mi = 0; mi < 4; ++mi)
#pragma unroll
      for (int ni = 0; ni < 4; ++ni)
        acc[mi][ni] = __builtin_amdgcn_mfma_f32_16x16x32_bf16(af[mi], bf[ni], acc[mi][ni], 0, 0, 0);

    asm volatile("s_waitcnt vmcnt(0) lgkmcnt(0)\n\ts_barrier" ::: "memory");
  }

  // ---- epilogue ----
  const float* n2 = nrm2 + (size_t)b * P_;
  float* ob = out + (size_t)b * P_ * P_;
  const int cl = lane & 15, rg4 = (lane >> 4) * 4;

  float rnq[4];
#pragma unroll
  for (int ni = 0; ni < 4; ++ni) {
    const int qc = q0 + wcol * 64 + ni * 16 + cl;
    rnq[ni] = __builtin_amdgcn_rcpf(fmaxf(sqrtf(n2[qc]), 1e-4f));
  }
  floatx4 rnp[4];
#pragma unroll
  for (int mi = 0; mi < 4; ++mi) {
    const float4 p2 = *reinterpret_cast<const float4*>(&n2[p0 + wrow * 64 + mi * 16 + rg4]);
    rnp[mi][0] = __builtin_amdgcn_rcpf(fmaxf(sqrtf(p2.x), 1e-4f));
    rnp[mi][1] = __builtin_amdgcn_rcpf(fmaxf(sqrtf(p2.y), 1e-4f));
    rnp[mi][2] = __builtin_amdgcn_rcpf(fmaxf(sqrtf(p2.z), 1e-4f));
    rnp[mi][3] = __builtin_amdgcn_rcpf(fmaxf(sqrtf(p2.w), 1e-4f));
  }

  // per-wave transposed bounce region reusing staging LDS (safe: final fenced
  // barrier above guarantees all waves' staging ds_reads completed; "memory"
  // clobber stops these writes hoisting above it). [64 q][20 p] fp32 per wave.
  float* etile = (float*)smem + wid * 1280;  // 4 waves x 5120B = 20KB < 32KB

#pragma unroll
  for (int mi = 0; mi < 4; ++mi) {
    const int prow = p0 + wrow * 64 + mi * 16 + rg4;
#pragma unroll
    for (int ni = 0; ni < 4; ++ni) {
      floatx4 vv = acc[mi][ni] * rnp[mi] * rnq[ni];
      const int qc = q0 + wcol * 64 + ni * 16 + cl;
      if (tm == tn) {
        const int d = qc - prow;  // diag when prow + r == qc
        if (d >= 0 && d < 4) vv[d] = 1.0f;
      }
      // normal tile: 4 scalar stores -> 4 x 64B segments per instruction
      ob[(size_t)(prow + 0) * P_ + qc] = vv[0];
      ob[(size_t)(prow + 1) * P_ + qc] = vv[1];
      ob[(size_t)(prow + 2) * P_ + qc] = vv[2];
      ob[(size_t)(prow + 3) * P_ + qc] = vv[3];
      if (tm != tn)  // stash transposed: lane's 4 consecutive p at row q
        *reinterpret_cast<floatx4*>(&etile[(ni * 16 + cl) * 20 + rg4]) = vv;
    }
    if (tm != tn) {
      // coalesced mirror store for this 16-col (p) slab: rows q, 64B segments
      const int pcb = p0 + wrow * 64 + mi * 16;
#pragma unroll
      for (int i = 0; i < 4; ++i) {
        const int qq = i * 16 + (lane >> 2);
        const floatx4 mv = *reinterpret_cast<const floatx4*>(&etile[qq * 20 + (lane & 3) * 4]);
        *reinterpret_cast<floatx4*>(
            &ob[(size_t)(q0 + wcol * 64 + qq) * P_ + pcb + (lane & 3) * 4]) = mv;
      }
    }
  }
}

extern "C" void kernel_launch(void* const* d_in, const int* in_sizes, int n_in,
                              void* d_out, int out_size, void* d_ws, size_t ws_size,
                              hipStream_t stream) {
  const float* x = (const float*)d_in[0];
  float* out = (float*)d_out;

  short* Xt = (short*)d_ws;                                                    // 16 MB
  float* nrm2 = (float*)((char*)d_ws + (size_t)B_ * P_ * C_ * sizeof(short));  // 128 KB

  k_transpose<<<dim3(P_ / 32, B_), dim3(32, 8), 0, stream>>>(x, Xt, nrm2);
  k_gemm<<<dim3(NT * B_), 256, 0, stream>>>(Xt, nrm2, out);
}

// Round 8
// 82.553 us; speedup vs baseline: 1.1202x; 1.1202x over previous
//
#include <hip/hip_runtime.h>

#define B_ 16
#define C_ 256
#define P_ 2048
#define BK 32
#define NT 136      // tiles per batch (120 strict-upper + 16 diag)
#define NT_OFF 120

typedef __attribute__((ext_vector_type(8))) short short8;
typedef __attribute__((ext_vector_type(4))) float floatx4;

// round-to-nearest-even fp32 -> bf16
__device__ inline short f2bf(float v) {
  union { float f; unsigned u; } c; c.f = v;
  unsigned r = c.u + 0x7fffu + ((c.u >> 16) & 1u);
  return (short)(r >> 16);
}

#define GLOAD_LDS16(g, l)                                          \
  __builtin_amdgcn_global_load_lds(                                \
      (const __attribute__((address_space(1))) void*)(g),          \
      (__attribute__((address_space(3))) void*)(l), 16, 0, 0)

// ---------------- kernel 1: transpose + fp32->bf16 + exact norms ----------------
// One block owns a 32-wide p-stripe of one batch; loops all 8 c-chunks.
// No atomics, no memset dispatch needed.
__global__ __launch_bounds__(256, 4) void k_transpose(const float* __restrict__ x,
                                                      short* __restrict__ Xt,
                                                      float* __restrict__ nrm2) {
  __shared__ float t[32][33];
  __shared__ float red[8][32];
  const int p0 = blockIdx.x * 32, b = blockIdx.y;
  const float* xb = x + (size_t)b * C_ * P_;
  short* xtb = Xt + (size_t)b * P_ * C_;
  const int tx = threadIdx.x, ty = threadIdx.y;  // block dim3(32,8)
  const int tid = ty * 32 + tx;
  const int r = tid >> 3, ch = tid & 7;
  float s = 0.f;
#pragma unroll 1
  for (int ci = 0; ci < 8; ++ci) {
    const int c0 = ci * 32;
#pragma unroll
    for (int i = 0; i < 4; ++i) {
      float v = xb[(size_t)(c0 + ty + i * 8) * P_ + p0 + tx];
      t[ty + i * 8][tx] = v;
      s += v * v;  // partial for col p0+tx
    }
    __syncthreads();
    short4 w;
    w.x = f2bf(t[ch * 4 + 0][r]);
    w.y = f2bf(t[ch * 4 + 1][r]);
    w.z = f2bf(t[ch * 4 + 2][r]);
    w.w = f2bf(t[ch * 4 + 3][r]);
    *reinterpret_cast<short4*>(&xtb[(size_t)(p0 + r) * C_ + c0 + ch * 4]) = w;
    __syncthreads();  // protect t before next chunk overwrites
  }
  red[ty][tx] = s;
  __syncthreads();
  if (tid < 32) {
    float ns = 0.f;
#pragma unroll
    for (int j = 0; j < 8; ++j) ns += red[j][tid];
    nrm2[b * P_ + p0 + tid] = ns;  // exact: all 256 c summed in this block
  }
}

// ---------------- kernel 2: symmetric Gram GEMM, XCD-chunked ----------------
__global__ __launch_bounds__(256, 3) void k_gemm(const short* __restrict__ Xt,
                                                 const float* __restrict__ nrm2,
                                                 float* __restrict__ out) {
  // XCD-chunked mapping: xcd = bid%8 owns 2 full batches -> staging L2-resident
  const int bid = blockIdx.x;
  const int xcd = bid & 7;
  const int s = bid >> 3;              // 0..271
  const int b = xcd * 2 + (s >= NT);   // 2 batches per XCD
  int t = s - (s >= NT ? NT : 0);      // 0..135

  int tm, tn;
  if (t < NT_OFF) {  // strict-upper tiles (2 writes) first
    int rem = t, len = 15;
    tm = 0;
    while (rem >= len) { rem -= len; --len; ++tm; }
    tn = tm + 1 + rem;
  } else {
    tm = tn = t - NT_OFF;
  }
  const int p0 = tm * 128, q0 = tn * 128;
  const short* Xb = Xt + (size_t)b * P_ * C_;

  __shared__ __align__(16) char smem[32768];  // As[2][8K] | Bs[2][8K]; epilogue reuse

  const int tid = threadIdx.x;
  const int lane = tid & 63;
  const int wid = tid >> 6;
  const int wrow = wid >> 1;  // p band (64)
  const int wcol = wid & 1;   // q band (64)

  floatx4 acc[4][4];
#pragma unroll
  for (int i = 0; i < 4; ++i)
#pragma unroll
    for (int j = 0; j < 4; ++j) acc[i][j] = (floatx4){0.f, 0.f, 0.f, 0.f};

  const int K2 = C_ * 2;  // row stride bytes

  auto STAGE = [&](int buf, int kt) {
    const int kb = kt * (BK * 2);
#pragma unroll
    for (int j = 0; j < 2; ++j) {
      const int chunk = j * 4 + wid;           // 0..7, wave-uniform
      const int f = chunk * 1024 + lane * 16;
      const int row = f >> 6;
      const int inrow = f & 63;
      GLOAD_LDS16((const char*)Xb + (size_t)(p0 + row) * K2 + kb + inrow,
                  smem + buf * 8192 + chunk * 1024);
      GLOAD_LDS16((const char*)Xb + (size_t)(q0 + row) * K2 + kb + inrow,
                  smem + 16384 + buf * 8192 + chunk * 1024);
    }
  };

  STAGE(0, 0);

  // r6's proven loop: counted vmcnt (prefetch never drained mid-loop) + the
  // lgkmcnt(0)-before-restage-barrier completion discipline (r3-r5 root cause:
  // ds_read ISSUE before a barrier is not COMPLETION; reads must land in VGPRs
  // before any wave may overwrite the buffer via global_load_lds).
  for (int kt = 0; kt < C_ / BK; ++kt) {
    const int cur = kt & 1;
    if (kt < C_ / BK - 1) {
      STAGE(cur ^ 1, kt + 1);
      // 8 outstanding; wait to <=4 -> my 4 cur-tile loads (oldest) landed
      asm volatile("s_waitcnt vmcnt(4)\n\ts_barrier" ::: "memory");
    } else {
      asm volatile("s_waitcnt vmcnt(0)\n\ts_barrier" ::: "memory");
    }

    const short* As = (const short*)(smem + cur * 8192);
    const short* Bs = (const short*)(smem + 16384 + cur * 8192);
    short8 af[4], bf[4];
#pragma unroll
    for (int mi = 0; mi < 4; ++mi) {
      const int r = wrow * 64 + mi * 16 + (lane & 15);
      af[mi] = *reinterpret_cast<const short8*>(&As[r * BK + (lane >> 4) * 8]);
    }
#pragma unroll
    for (int ni = 0; ni < 4; ++ni) {
      const int r = wcol * 64 + ni * 16 + (lane & 15);
      bf[ni] = *reinterpret_cast<const short8*>(&Bs[r * BK + (lane >> 4) * 8]);
    }
    // D[row=p][col=q]; C/D layout: col=lane&15, row=(lane>>4)*4+reg (verified r1)
#pragma unroll
    for (int mi = 0; mi < 4; ++mi)
#pragma unroll
      for (int ni = 0; ni < 4; ++ni)
        acc[mi][ni] = __builtin_amdgcn_mfma_f32_16x16x32_bf16(af[mi], bf[ni], acc[mi][ni], 0, 0, 0);

    asm volatile("s_waitcnt lgkmcnt(0)\n\ts_barrier" ::: "memory");
  }

  // ---- epilogue ----
  const float* n2 = nrm2 + (size_t)b * P_;
  float* ob = out + (size_t)b * P_ * P_;
  const int cl = lane & 15, rg4 = (lane >> 4) * 4;

  float rnq[4];
#pragma unroll
  for (int ni = 0; ni < 4; ++ni) {
    const int qc = q0 + wcol * 64 + ni * 16 + cl;
    rnq[ni] = __builtin_amdgcn_rcpf(fmaxf(sqrtf(n2[qc]), 1e-4f));
  }
  floatx4 rnp[4];
#pragma unroll
  for (int mi = 0; mi < 4; ++mi) {
    const float4 p2 = *reinterpret_cast<const float4*>(&n2[p0 + wrow * 64 + mi * 16 + rg4]);
    rnp[mi][0] = __builtin_amdgcn_rcpf(fmaxf(sqrtf(p2.x), 1e-4f));
    rnp[mi][1] = __builtin_amdgcn_rcpf(fmaxf(sqrtf(p2.y), 1e-4f));
    rnp[mi][2] = __builtin_amdgcn_rcpf(fmaxf(sqrtf(p2.z), 1e-4f));
    rnp[mi][3] = __builtin_amdgcn_rcpf(fmaxf(sqrtf(p2.w), 1e-4f));
  }

  // per-wave transposed bounce region reusing staging LDS (safe: final fenced
  // barrier guarantees all waves' staging ds_reads completed; the "memory"
  // clobber stops these writes hoisting above it). [64 q][20 p] fp32 per wave.
  float* etile = (float*)smem + wid * 1280;  // 4 x 5120B = 20KB < 32KB

#pragma unroll
  for (int mi = 0; mi < 4; ++mi) {
    const int prow = p0 + wrow * 64 + mi * 16 + rg4;
#pragma unroll
    for (int ni = 0; ni < 4; ++ni) {
      floatx4 vv = acc[mi][ni] * rnp[mi] * rnq[ni];
      const int qc = q0 + wcol * 64 + ni * 16 + cl;
      if (tm == tn) {
        const int d = qc - prow;  // diag when prow + r == qc
        if (d >= 0 && d < 4) vv[d] = 1.0f;
      }
      // normal tile: 4 scalar stores -> 4 x 64B segments per instruction
      ob[(size_t)(prow + 0) * P_ + qc] = vv[0];
      ob[(size_t)(prow + 1) * P_ + qc] = vv[1];
      ob[(size_t)(prow + 2) * P_ + qc] = vv[2];
      ob[(size_t)(prow + 3) * P_ + qc] = vv[3];
      if (tm != tn)  // stash transposed: lane's 4 consecutive p at row q
        *reinterpret_cast<floatx4*>(&etile[(ni * 16 + cl) * 20 + rg4]) = vv;
    }
    if (tm != tn) {
      // coalesced mirror store for this 16-col (p) slab: rows q, 64B segments
      const int pcb = p0 + wrow * 64 + mi * 16;
#pragma unroll
      for (int i = 0; i < 4; ++i) {
        const int qq = i * 16 + (lane >> 2);
        const floatx4 mv = *reinterpret_cast<const floatx4*>(&etile[qq * 20 + (lane & 3) * 4]);
        *reinterpret_cast<floatx4*>(
            &ob[(size_t)(q0 + wcol * 64 + qq) * P_ + pcb + (lane & 3) * 4]) = mv;
      }
    }
  }
}

extern "C" void kernel_launch(void* const* d_in, const int* in_sizes, int n_in,
                              void* d_out, int out_size, void* d_ws, size_t ws_size,
                              hipStream_t stream) {
  const float* x = (const float*)d_in[0];
  float* out = (float*)d_out;

  short* Xt = (short*)d_ws;                                                    // 16 MB
  float* nrm2 = (float*)((char*)d_ws + (size_t)B_ * P_ * C_ * sizeof(short));  // 128 KB

  k_transpose<<<dim3(P_ / 32, B_), dim3(32, 8), 0, stream>>>(x, Xt, nrm2);
  k_gemm<<<dim3(NT * B_), 256, 0, stream>>>(Xt, nrm2, out);
}